// Round 1
// baseline (737.550 us; speedup 1.0000x reference)
//
#include <hip/hip_runtime.h>
#include <hip/hip_bf16.h>
#include <math.h>

#define T_TOK 1024
#define HDIM 2048
#define NEXP 8
#define IDIM 1408
#define ISH  2816
#define EI   (NEXP*IDIM)   // 11264

typedef __attribute__((ext_vector_type(8))) short bf16x8;
typedef __attribute__((ext_vector_type(4))) float f32x4;

static __device__ __forceinline__ unsigned short f2bf(float f) {
  union { float f; unsigned u; } a; a.f = f;
  unsigned u = a.u;
  unsigned lsb = (u >> 16) & 1u;
  u += 0x7fffu + lsb;          // round-to-nearest-even
  return (unsigned short)(u >> 16);
}

// ---------------- router: exact fp32 logits, softmax, top-2, combine weights ----------------
__global__ __launch_bounds__(256) void router_kernel(
    const float* __restrict__ x,    // [T][H]
    const float* __restrict__ rw,   // [E][H]
    float* __restrict__ logits_out, // [T][E]
    float* __restrict__ cw)         // [T][E]
{
  int t = blockIdx.x;
  int tid = threadIdx.x;
  float part[NEXP];
  const float* xr = x + (size_t)t * HDIM + tid * 8;
  float4 xa = *reinterpret_cast<const float4*>(xr);
  float4 xb = *reinterpret_cast<const float4*>(xr + 4);
  for (int e = 0; e < NEXP; ++e) {
    const float* wp = rw + (size_t)e * HDIM + tid * 8;
    float4 wa = *reinterpret_cast<const float4*>(wp);
    float4 wb = *reinterpret_cast<const float4*>(wp + 4);
    part[e] = xa.x*wa.x + xa.y*wa.y + xa.z*wa.z + xa.w*wa.w
            + xb.x*wb.x + xb.y*wb.y + xb.z*wb.z + xb.w*wb.w;
  }
  for (int e = 0; e < NEXP; ++e)
    for (int off = 32; off; off >>= 1)
      part[e] += __shfl_xor(part[e], off, 64);
  __shared__ float sums[4][NEXP];
  int wid = tid >> 6, lane = tid & 63;
  if (lane == 0) for (int e = 0; e < NEXP; ++e) sums[wid][e] = part[e];
  __syncthreads();
  if (tid == 0) {
    float lg[NEXP];
    for (int e = 0; e < NEXP; ++e) lg[e] = sums[0][e] + sums[1][e] + sums[2][e] + sums[3][e];
    float mx = lg[0];
    for (int e = 1; e < NEXP; ++e) mx = fmaxf(mx, lg[e]);
    float p[NEXP], s = 0.f;
    for (int e = 0; e < NEXP; ++e) { p[e] = expf(lg[e] - mx); s += p[e]; }
    for (int e = 0; e < NEXP; ++e) p[e] /= s;
    // top-2 on logits (same order as scores; lowest index wins ties)
    int i1 = 0;
    for (int e = 1; e < NEXP; ++e) if (lg[e] > lg[i1]) i1 = e;
    int i2 = -1;
    for (int e = 0; e < NEXP; ++e) { if (e == i1) continue; if (i2 < 0 || lg[e] > lg[i2]) i2 = e; }
    float denom = p[i1] + p[i2] + 1e-6f;
    for (int e = 0; e < NEXP; ++e) {
      float v = (e == i1) ? p[i1] / denom : (e == i2) ? p[i2] / denom : 0.f;
      cw[t * NEXP + e] = v;
      logits_out[t * NEXP + e] = lg[e];
    }
  }
}

// ---------------- fp32 -> bf16 convert (hidden states) ----------------
__global__ __launch_bounds__(256) void cvt_kernel(
    const float* __restrict__ x, unsigned short* __restrict__ xb, int n)
{
  int i = (blockIdx.x * blockDim.x + threadIdx.x) * 4;
  if (i < n) {
    float4 v = *reinterpret_cast<const float4*>(x + i);
    ushort4 p = { f2bf(v.x), f2bf(v.y), f2bf(v.z), f2bf(v.w) };
    *reinterpret_cast<ushort4*>(xb + i) = p;
  }
}

// ---------------- gate+up fused SwiGLU: h = cw * silu(x@Wg^T) * (x@Wu^T) ----------------
// A: xb [T][H] bf16.  B: wg/wu [z][N][H] fp32 (row-major, K=H inner).
// out: bf16, row stride ldh, column offset z*Ndim.
template<bool HAS_CW>
__global__ __launch_bounds__(256) void gu_kernel(
    const unsigned short* __restrict__ xb,
    const float* __restrict__ wg_all,
    const float* __restrict__ wu_all,
    const float* __restrict__ cw,
    unsigned short* __restrict__ hout,
    int Ndim, int ldh)
{
  int e = blockIdx.z;
  const float* wg = wg_all + (size_t)e * Ndim * HDIM;
  const float* wu = wu_all + (size_t)e * Ndim * HDIM;
  unsigned short* hptr = hout + (size_t)e * Ndim;
  int m0 = blockIdx.y * 64;
  int n0 = blockIdx.x * 64;

  __shared__ unsigned short As[64][40];
  __shared__ unsigned short Bg[64][40];
  __shared__ unsigned short Bu[64][40];

  int tid = threadIdx.x;
  int lane = tid & 63;
  int wid = tid >> 6;
  int wr = wid >> 1, wc = wid & 1;

  f32x4 accg[2][2] = {};
  f32x4 accu[2][2] = {};

  for (int k0 = 0; k0 < HDIM; k0 += 32) {
    {
      int r = tid >> 2;
      int c = (tid & 3) * 8;
      *reinterpret_cast<uint4*>(&As[r][c]) =
          *reinterpret_cast<const uint4*>(xb + (size_t)(m0 + r) * HDIM + k0 + c);
    }
    for (int h = 0; h < 2; ++h) {
      int cid = tid * 2 + h;
      int r = cid >> 3;
      int c = (cid & 7) * 4;
      float4 vg = *reinterpret_cast<const float4*>(wg + (size_t)(n0 + r) * HDIM + k0 + c);
      float4 vu = *reinterpret_cast<const float4*>(wu + (size_t)(n0 + r) * HDIM + k0 + c);
      ushort4 pg = { f2bf(vg.x), f2bf(vg.y), f2bf(vg.z), f2bf(vg.w) };
      ushort4 pu = { f2bf(vu.x), f2bf(vu.y), f2bf(vu.z), f2bf(vu.w) };
      *reinterpret_cast<ushort4*>(&Bg[r][c]) = pg;
      *reinterpret_cast<ushort4*>(&Bu[r][c]) = pu;
    }
    __syncthreads();
    int fr = lane & 15;
    int fk = (lane >> 4) * 8;
    bf16x8 a[2], bg[2], bu[2];
    for (int m = 0; m < 2; ++m)
      a[m] = *reinterpret_cast<const bf16x8*>(&As[wr*32 + m*16 + fr][fk]);
    for (int n = 0; n < 2; ++n) {
      bg[n] = *reinterpret_cast<const bf16x8*>(&Bg[wc*32 + n*16 + fr][fk]);
      bu[n] = *reinterpret_cast<const bf16x8*>(&Bu[wc*32 + n*16 + fr][fk]);
    }
    for (int m = 0; m < 2; ++m)
      for (int n = 0; n < 2; ++n) {
        accg[m][n] = __builtin_amdgcn_mfma_f32_16x16x32_bf16(a[m], bg[n], accg[m][n], 0, 0, 0);
        accu[m][n] = __builtin_amdgcn_mfma_f32_16x16x32_bf16(a[m], bu[n], accu[m][n], 0, 0, 0);
      }
    __syncthreads();
  }
  int fq = lane >> 4;
  int fc = lane & 15;
  for (int m = 0; m < 2; ++m)
    for (int n = 0; n < 2; ++n)
      for (int j = 0; j < 4; ++j) {
        int row = wr*32 + m*16 + fq*4 + j;
        int col = wc*32 + n*16 + fc;
        int tok = m0 + row;
        float g = accg[m][n][j], u = accu[m][n][j];
        float hval = g / (1.f + __expf(-g)) * u;
        if (HAS_CW) hval *= cw[tok * NEXP + e];
        hptr[(size_t)tok * ldh + n0 + col] = f2bf(hval);
      }
}

// ---------------- down proj (+combine): out (+)= h @ Wd^T ----------------
// MOE: wdn = w_down [E][H][I], k = e*I+i -> B(n,k)=w_down[e][n][i]
// else: wdn = sw_down [H][IS],            B(n,k)=sw_down[n][k]
template<bool MOE, bool ADD>
__global__ __launch_bounds__(256) void dn_kernel(
    const unsigned short* __restrict__ hmat, // [T][Ktot] bf16
    const float* __restrict__ wdn,
    float* __restrict__ out,                 // [T][H] fp32
    int Ktot)
{
  int m0 = blockIdx.y * 64;
  int n0 = blockIdx.x * 64;
  __shared__ unsigned short As[64][40];
  __shared__ unsigned short Bs[64][40];
  int tid = threadIdx.x;
  int lane = tid & 63;
  int wid = tid >> 6;
  int wr = wid >> 1, wc = wid & 1;
  f32x4 acc[2][2] = {};
  for (int k0 = 0; k0 < Ktot; k0 += 32) {
    {
      int r = tid >> 2;
      int c = (tid & 3) * 8;
      *reinterpret_cast<uint4*>(&As[r][c]) =
          *reinterpret_cast<const uint4*>(hmat + (size_t)(m0 + r) * Ktot + k0 + c);
    }
    const float* brow;
    int bstride;
    if (MOE) {
      int e = k0 / IDIM;
      int i0 = k0 - e * IDIM;
      brow = wdn + (size_t)e * HDIM * IDIM + (size_t)n0 * IDIM + i0;
      bstride = IDIM;
    } else {
      brow = wdn + (size_t)n0 * Ktot + k0;
      bstride = Ktot;
    }
    for (int h = 0; h < 2; ++h) {
      int cid = tid * 2 + h;
      int r = cid >> 3;
      int c = (cid & 7) * 4;
      float4 v = *reinterpret_cast<const float4*>(brow + (size_t)r * bstride + c);
      ushort4 p = { f2bf(v.x), f2bf(v.y), f2bf(v.z), f2bf(v.w) };
      *reinterpret_cast<ushort4*>(&Bs[r][c]) = p;
    }
    __syncthreads();
    int fr = lane & 15;
    int fk = (lane >> 4) * 8;
    bf16x8 a[2], b[2];
    for (int m = 0; m < 2; ++m)
      a[m] = *reinterpret_cast<const bf16x8*>(&As[wr*32 + m*16 + fr][fk]);
    for (int n = 0; n < 2; ++n)
      b[n] = *reinterpret_cast<const bf16x8*>(&Bs[wc*32 + n*16 + fr][fk]);
    for (int m = 0; m < 2; ++m)
      for (int n = 0; n < 2; ++n)
        acc[m][n] = __builtin_amdgcn_mfma_f32_16x16x32_bf16(a[m], b[n], acc[m][n], 0, 0, 0);
    __syncthreads();
  }
  int fq = lane >> 4, fc = lane & 15;
  for (int m = 0; m < 2; ++m)
    for (int n = 0; n < 2; ++n)
      for (int j = 0; j < 4; ++j) {
        int row = wr*32 + m*16 + fq*4 + j;
        int col = wc*32 + n*16 + fc;
        size_t o = (size_t)(m0 + row) * HDIM + n0 + col;
        float v = acc[m][n][j];
        out[o] = ADD ? out[o] + v : v;
      }
}

extern "C" void kernel_launch(void* const* d_in, const int* in_sizes, int n_in,
                              void* d_out, int out_size, void* d_ws, size_t ws_size,
                              hipStream_t stream) {
  const float* x      = (const float*)d_in[0];
  const float* rw     = (const float*)d_in[1];
  const float* w_gate = (const float*)d_in[2];
  const float* w_up   = (const float*)d_in[3];
  const float* w_down = (const float*)d_in[4];
  const float* sw_g   = (const float*)d_in[5];
  const float* sw_u   = (const float*)d_in[6];
  const float* sw_d   = (const float*)d_in[7];
  float* out_final  = (float*)d_out;                      // [T][H]
  float* out_logits = out_final + (size_t)T_TOK * HDIM;   // [T][E]

  char* ws = (char*)d_ws;
  float* cw = (float*)ws;                                             // 32 KB
  unsigned short* xb   = (unsigned short*)(ws + (32 << 10));          // 4 MB
  unsigned short* hmoe = (unsigned short*)(ws + (32 << 10) + (size_t)T_TOK * HDIM * 2);
  unsigned short* hsh  = (unsigned short*)((char*)hmoe + (size_t)T_TOK * EI * 2);

  router_kernel<<<T_TOK, 256, 0, stream>>>(x, rw, out_logits, cw);
  cvt_kernel<<<(T_TOK * HDIM / 4 + 255) / 256, 256, 0, stream>>>(x, xb, T_TOK * HDIM);

  dim3 g_moe(IDIM / 64, T_TOK / 64, NEXP);
  gu_kernel<true><<<g_moe, 256, 0, stream>>>(xb, w_gate, w_up, cw, hmoe, IDIM, EI);

  dim3 g_sh(ISH / 64, T_TOK / 64, 1);
  gu_kernel<false><<<g_sh, 256, 0, stream>>>(xb, sw_g, sw_u, nullptr, hsh, ISH, ISH);

  dim3 g_dn(HDIM / 64, T_TOK / 64, 1);
  dn_kernel<true,  false><<<g_dn, 256, 0, stream>>>(hmoe, w_down, out_final, EI);
  dn_kernel<false, true ><<<g_dn, 256, 0, stream>>>(hsh,  sw_d,   out_final, ISH);
}

// Round 2
// 276.517 us; speedup vs baseline: 2.6673x; 2.6673x over previous
//
#include <hip/hip_runtime.h>
#include <hip/hip_bf16.h>
#include <math.h>

#define T_TOK 1024
#define HDIM  2048
#define NEXP  8
#define IDIM  1408
#define ISH   2816
#define ROW_CAP 3072          // MoE gathered rows capacity (24 tiles of 128)
#define ROWS_ALL 4096         // + 1024 shared rows
#define MOE_TILES 24
#define NT_TOT 32

typedef __attribute__((ext_vector_type(8))) short bf16x8;
typedef __attribute__((ext_vector_type(4))) float f32x4;

static __device__ __forceinline__ unsigned short f2bf(float f) {
  __hip_bfloat16 h = __float2bfloat16(f);   // RTNE; compiler emits v_cvt_pk
  return __builtin_bit_cast(unsigned short, h);
}

// ---------------- router: exact fp32 logits, softmax, top-2 ----------------
__global__ __launch_bounds__(256) void router_kernel(
    const float* __restrict__ x, const float* __restrict__ rw,
    float* __restrict__ logits_out, int* __restrict__ selk, float* __restrict__ cwk)
{
  int t = blockIdx.x;
  int tid = threadIdx.x;
  float part[NEXP];
  const float* xr = x + (size_t)t * HDIM + tid * 8;
  float4 xa = *reinterpret_cast<const float4*>(xr);
  float4 xb = *reinterpret_cast<const float4*>(xr + 4);
  for (int e = 0; e < NEXP; ++e) {
    const float* wp = rw + (size_t)e * HDIM + tid * 8;
    float4 wa = *reinterpret_cast<const float4*>(wp);
    float4 wb = *reinterpret_cast<const float4*>(wp + 4);
    part[e] = xa.x*wa.x + xa.y*wa.y + xa.z*wa.z + xa.w*wa.w
            + xb.x*wb.x + xb.y*wb.y + xb.z*wb.z + xb.w*wb.w;
  }
  for (int e = 0; e < NEXP; ++e)
    for (int off = 32; off; off >>= 1)
      part[e] += __shfl_xor(part[e], off, 64);
  __shared__ float sums[4][NEXP];
  int wid = tid >> 6, lane = tid & 63;
  if (lane == 0) for (int e = 0; e < NEXP; ++e) sums[wid][e] = part[e];
  __syncthreads();
  if (tid == 0) {
    float lg[NEXP];
    for (int e = 0; e < NEXP; ++e) lg[e] = sums[0][e] + sums[1][e] + sums[2][e] + sums[3][e];
    float mx = lg[0];
    for (int e = 1; e < NEXP; ++e) mx = fmaxf(mx, lg[e]);
    float p[NEXP], s = 0.f;
    for (int e = 0; e < NEXP; ++e) { p[e] = expf(lg[e] - mx); s += p[e]; }
    for (int e = 0; e < NEXP; ++e) p[e] /= s;
    int i1 = 0;
    for (int e = 1; e < NEXP; ++e) if (lg[e] > lg[i1]) i1 = e;
    int i2 = -1;
    for (int e = 0; e < NEXP; ++e) { if (e == i1) continue; if (i2 < 0 || lg[e] > lg[i2]) i2 = e; }
    float denom = p[i1] + p[i2] + 1e-6f;
    selk[t*2] = i1; selk[t*2+1] = i2;
    cwk[t*2] = p[i1] / denom; cwk[t*2+1] = p[i2] / denom;
    for (int e = 0; e < NEXP; ++e) logits_out[t * NEXP + e] = lg[e];
  }
}

// ---------------- plan: counts, 128-aligned segments, row assignment, tile table ----------------
__global__ __launch_bounds__(512) void plan_kernel(
    const int* __restrict__ selk, const float* __restrict__ cwk,
    int* __restrict__ rowidx, int* __restrict__ tok_of_row,
    float* __restrict__ rowwgt, int* __restrict__ tile_tab)
{
  __shared__ int cnt[NEXP];
  __shared__ int seg[NEXP];
  int tid = threadIdx.x;
  int w = tid >> 6, lane = tid & 63;
  for (int i = tid; i < ROW_CAP; i += 512) { tok_of_row[i] = -1; rowwgt[i] = 0.f; }
  for (int i = tid; i < T_TOK; i += 512) { tok_of_row[ROW_CAP + i] = i; rowwgt[ROW_CAP + i] = 1.f; }
  // count (wave w handles expert w)
  int total = 0;
  for (int base = 0; base < 2 * T_TOK; base += 64) {
    unsigned long long m = __ballot(selk[base + lane] == w);
    total += __popcll(m);
  }
  if (lane == 0) cnt[w] = total;
  __syncthreads();
  if (tid == 0) {
    int s = 0;
    for (int e = 0; e < NEXP; ++e) { seg[e] = s; s += (cnt[e] + 127) & ~127; }
  }
  __syncthreads();
  // assign rows in (t,slot) order
  int run = seg[w];
  for (int base = 0; base < 2 * T_TOK; base += 64) {
    int i = base + lane;
    bool f = selk[i] == w;
    unsigned long long m = __ballot(f);
    if (f) {
      int r = run + __popcll(m & ((1ull << lane) - 1ull));
      rowidx[i] = r;
      tok_of_row[r] = i >> 1;
      rowwgt[r] = cwk[i];
    }
    run += __popcll(m);
  }
  __syncthreads();
  if (tid < NT_TOT) {
    int e = -1, valid = 0;
    if (tid < MOE_TILES) {
      int base = tid * 128;
      for (int k = 0; k < NEXP; ++k) {
        int s0 = seg[k], s1 = s0 + ((cnt[k] + 127) & ~127);
        if (base >= s0 && base < s1) {
          e = k;
          valid = cnt[k] - (base - s0);
          if (valid > 128) valid = 128;
          if (valid < 0) valid = 0;
        }
      }
    } else { e = 0; valid = 128; }
    tile_tab[tid*2] = e;
    tile_tab[tid*2+1] = valid;
  }
}

// ---------------- gather: x rows -> bf16 gathered matrix (MoE rows + shared rows) ----------------
__global__ __launch_bounds__(256) void gather_kernel(
    const float* __restrict__ x, const int* __restrict__ tok_of_row,
    unsigned short* __restrict__ xg)
{
  int r = blockIdx.x;
  int tid = threadIdx.x;
  int tok = tok_of_row[r];
  unsigned short* dst = xg + (size_t)r * HDIM + tid * 8;
  union { unsigned short us[8]; uint4 q; } p;
  if (tok < 0) {
    p.q = uint4{0, 0, 0, 0};
  } else {
    const float* src = x + (size_t)tok * HDIM + tid * 8;
    float4 a = *reinterpret_cast<const float4*>(src);
    float4 b = *reinterpret_cast<const float4*>(src + 4);
    p.us[0]=f2bf(a.x); p.us[1]=f2bf(a.y); p.us[2]=f2bf(a.z); p.us[3]=f2bf(a.w);
    p.us[4]=f2bf(b.x); p.us[5]=f2bf(b.y); p.us[6]=f2bf(b.z); p.us[7]=f2bf(b.w);
  }
  *reinterpret_cast<uint4*>(dst) = p.q;
}

// ---- stage one 128x64 fp32 B-panel row-chunk into padded bf16 LDS tile ----
static __device__ __forceinline__ void stage_b(
    const float* __restrict__ src, unsigned short (*Bs)[72], int brow, int bc)
{
  float4 v0 = *reinterpret_cast<const float4*>(src);
  float4 v1 = *reinterpret_cast<const float4*>(src + 4);
  float4 v2 = *reinterpret_cast<const float4*>(src + 8);
  float4 v3 = *reinterpret_cast<const float4*>(src + 12);
  union { unsigned short us[8]; uint4 q; } a, b;
  a.us[0]=f2bf(v0.x); a.us[1]=f2bf(v0.y); a.us[2]=f2bf(v0.z); a.us[3]=f2bf(v0.w);
  a.us[4]=f2bf(v1.x); a.us[5]=f2bf(v1.y); a.us[6]=f2bf(v1.z); a.us[7]=f2bf(v1.w);
  b.us[0]=f2bf(v2.x); b.us[1]=f2bf(v2.y); b.us[2]=f2bf(v2.z); b.us[3]=f2bf(v2.w);
  b.us[4]=f2bf(v3.x); b.us[5]=f2bf(v3.y); b.us[6]=f2bf(v3.z); b.us[7]=f2bf(v3.w);
  *reinterpret_cast<uint4*>(&Bs[brow][bc]) = a.q;
  *reinterpret_cast<uint4*>(&Bs[brow][bc + 8]) = b.q;
}

// ---- A tile stage: global_load_lds, linear LDS dest, XOR-swizzled global source ----
static __device__ __forceinline__ void stage_a(
    const unsigned short* __restrict__ abase, size_t lda, int k0,
    unsigned short* As, int wid, int lane)
{
  #pragma unroll
  for (int j = 0; j < 2; ++j) {
    int row = j * 64 + wid * 8 + (lane >> 3);
    int col = ((lane & 7) ^ (row & 7)) << 3;
    const unsigned short* src = abase + (size_t)row * lda + k0 + col;
    unsigned short* dst = &As[(j * 64 + wid * 8) * 64];   // wave-uniform
    __builtin_amdgcn_global_load_lds(
        (const __attribute__((address_space(1))) void*)src,
        (__attribute__((address_space(3))) void*)dst, 16, 0, 0);
  }
}

// ---------------- grouped gate+up SwiGLU (MoE tiles + shared tiles) ----------------
__global__ __launch_bounds__(512) void gu_kernel(
    const unsigned short* __restrict__ xg,
    const float* __restrict__ w_gate, const float* __restrict__ w_up,
    const float* __restrict__ sw_gate, const float* __restrict__ sw_up,
    const float* __restrict__ rowwgt, const int* __restrict__ tile_tab,
    unsigned short* __restrict__ hg, unsigned short* __restrict__ hsh)
{
  int mt = blockIdx.y, nt = blockIdx.x;
  int e = tile_tab[mt*2], valid = tile_tab[mt*2+1];
  bool sh = mt >= MOE_TILES;
  int ntiles = sh ? (ISH / 128) : (IDIM / 128);
  if (valid <= 0 || nt >= ntiles) return;
  int m0 = mt * 128, n0 = nt * 128;
  const float *wg, *wu; unsigned short* hout; int ldo;
  if (sh) { wg = sw_gate; wu = sw_up; hout = hsh + (size_t)(m0 - ROW_CAP) * ISH; ldo = ISH; }
  else {
    size_t wo = (size_t)e * IDIM * HDIM;
    wg = w_gate + wo; wu = w_up + wo;
    hout = hg + (size_t)m0 * IDIM; ldo = IDIM;
  }

  __shared__ unsigned short As[128 * 64];
  __shared__ unsigned short BgS[128][72];
  __shared__ unsigned short BuS[128][72];

  int tid = threadIdx.x, wid = tid >> 6, lane = tid & 63;
  int wr = wid >> 2, wc = wid & 3;
  int fr = lane & 15, fq8 = (lane >> 4) << 3;

  f32x4 accg[4][2] = {{}};
  f32x4 accu[4][2] = {{}};

  int brow = tid >> 2, bc = (tid & 3) << 4;
  const float* gsrc = wg + (size_t)(n0 + brow) * HDIM + bc;
  const float* usrc = wu + (size_t)(n0 + brow) * HDIM + bc;
  const unsigned short* abase = xg + (size_t)m0 * HDIM;

  for (int k0 = 0; k0 < HDIM; k0 += 64) {
    stage_a(abase, HDIM, k0, As, wid, lane);
    stage_b(gsrc + k0, BgS, brow, bc);
    stage_b(usrc + k0, BuS, brow, bc);
    __syncthreads();
    #pragma unroll
    for (int kk = 0; kk < 64; kk += 32) {
      bf16x8 a[4], bg[2], bu[2];
      #pragma unroll
      for (int m = 0; m < 4; ++m) {
        int row = wr * 64 + m * 16 + fr;
        a[m] = *reinterpret_cast<const bf16x8*>(&As[row * 64 + ((kk + fq8) ^ ((row & 7) << 3))]);
      }
      #pragma unroll
      for (int n = 0; n < 2; ++n) {
        bg[n] = *reinterpret_cast<const bf16x8*>(&BgS[wc * 32 + n * 16 + fr][kk + fq8]);
        bu[n] = *reinterpret_cast<const bf16x8*>(&BuS[wc * 32 + n * 16 + fr][kk + fq8]);
      }
      #pragma unroll
      for (int m = 0; m < 4; ++m)
        #pragma unroll
        for (int n = 0; n < 2; ++n) {
          accg[m][n] = __builtin_amdgcn_mfma_f32_16x16x32_bf16(a[m], bg[n], accg[m][n], 0, 0, 0);
          accu[m][n] = __builtin_amdgcn_mfma_f32_16x16x32_bf16(a[m], bu[n], accu[m][n], 0, 0, 0);
        }
    }
    __syncthreads();
  }
  int fq = lane >> 4;
  #pragma unroll
  for (int m = 0; m < 4; ++m)
    #pragma unroll
    for (int j = 0; j < 4; ++j) {
      int grow = wr * 64 + m * 16 + fq * 4 + j;
      float wv = rowwgt[m0 + grow];
      #pragma unroll
      for (int n = 0; n < 2; ++n) {
        float g = accg[m][n][j], u = accu[m][n][j];
        float hv = g / (1.f + __expf(-g)) * u * wv;
        hout[(size_t)grow * ldo + n0 + wc * 32 + n * 16 + fr] = f2bf(hv);
      }
    }
}

// ---------------- grouped down-proj (MoE -> ydn rows; shared -> out directly) ----------------
__global__ __launch_bounds__(512) void dn_kernel(
    const unsigned short* __restrict__ hg, const unsigned short* __restrict__ hsh,
    const float* __restrict__ w_down, const float* __restrict__ sw_down,
    const int* __restrict__ tile_tab,
    float* __restrict__ ydn, float* __restrict__ outf)
{
  int mt = blockIdx.y, nt = blockIdx.x;
  int e = tile_tab[mt*2], valid = tile_tab[mt*2+1];
  bool sh = mt >= MOE_TILES;
  if (valid <= 0) return;
  int m0 = mt * 128, n0 = nt * 128;
  const unsigned short* abase; const float* bbase; int K; float* obase;
  if (sh) { abase = hsh + (size_t)(m0 - ROW_CAP) * ISH; K = ISH; bbase = sw_down; obase = outf + (size_t)(m0 - ROW_CAP) * HDIM; }
  else { abase = hg + (size_t)m0 * IDIM; K = IDIM; bbase = w_down + (size_t)e * HDIM * IDIM; obase = ydn + (size_t)m0 * HDIM; }

  __shared__ unsigned short As[128 * 64];
  __shared__ unsigned short BsS[128][72];

  int tid = threadIdx.x, wid = tid >> 6, lane = tid & 63;
  int wr = wid >> 2, wc = wid & 3;
  int fr = lane & 15, fq8 = (lane >> 4) << 3;

  f32x4 acc[4][2] = {{}};

  int brow = tid >> 2, bc = (tid & 3) << 4;
  const float* bsrc = bbase + (size_t)(n0 + brow) * K + bc;

  for (int k0 = 0; k0 < K; k0 += 64) {
    stage_a(abase, K, k0, As, wid, lane);
    stage_b(bsrc + k0, BsS, brow, bc);
    __syncthreads();
    #pragma unroll
    for (int kk = 0; kk < 64; kk += 32) {
      bf16x8 a[4], b[2];
      #pragma unroll
      for (int m = 0; m < 4; ++m) {
        int row = wr * 64 + m * 16 + fr;
        a[m] = *reinterpret_cast<const bf16x8*>(&As[row * 64 + ((kk + fq8) ^ ((row & 7) << 3))]);
      }
      #pragma unroll
      for (int n = 0; n < 2; ++n)
        b[n] = *reinterpret_cast<const bf16x8*>(&BsS[wc * 32 + n * 16 + fr][kk + fq8]);
      #pragma unroll
      for (int m = 0; m < 4; ++m)
        #pragma unroll
        for (int n = 0; n < 2; ++n)
          acc[m][n] = __builtin_amdgcn_mfma_f32_16x16x32_bf16(a[m], b[n], acc[m][n], 0, 0, 0);
    }
    __syncthreads();
  }
  int fq = lane >> 4;
  #pragma unroll
  for (int m = 0; m < 4; ++m)
    #pragma unroll
    for (int j = 0; j < 4; ++j) {
      int grow = wr * 64 + m * 16 + fq * 4 + j;
      #pragma unroll
      for (int n = 0; n < 2; ++n)
        obase[(size_t)grow * HDIM + n0 + wc * 32 + n * 16 + fr] = acc[m][n][j];
    }
}

// ---------------- combine: out[t] += ydn[row0(t)] + ydn[row1(t)] ----------------
__global__ __launch_bounds__(256) void combine_kernel(
    const float* __restrict__ ydn, const int* __restrict__ rowidx,
    float* __restrict__ outf)
{
  int t = blockIdx.x;
  int c = threadIdx.x * 8;
  int r0 = rowidx[t*2], r1 = rowidx[t*2+1];
  const float4* a0 = reinterpret_cast<const float4*>(ydn + (size_t)r0 * HDIM + c);
  const float4* a1 = reinterpret_cast<const float4*>(ydn + (size_t)r1 * HDIM + c);
  float4* o = reinterpret_cast<float4*>(outf + (size_t)t * HDIM + c);
  float4 x0 = a0[0], x1 = a0[1], y0 = a1[0], y1 = a1[1];
  float4 o0 = o[0], o1 = o[1];
  o0.x += x0.x + y0.x; o0.y += x0.y + y0.y; o0.z += x0.z + y0.z; o0.w += x0.w + y0.w;
  o1.x += x1.x + y1.x; o1.y += x1.y + y1.y; o1.z += x1.z + y1.z; o1.w += x1.w + y1.w;
  o[0] = o0; o[1] = o1;
}

extern "C" void kernel_launch(void* const* d_in, const int* in_sizes, int n_in,
                              void* d_out, int out_size, void* d_ws, size_t ws_size,
                              hipStream_t stream) {
  const float* x      = (const float*)d_in[0];
  const float* rw     = (const float*)d_in[1];
  const float* w_gate = (const float*)d_in[2];
  const float* w_up   = (const float*)d_in[3];
  const float* w_down = (const float*)d_in[4];
  const float* sw_g   = (const float*)d_in[5];
  const float* sw_u   = (const float*)d_in[6];
  const float* sw_d   = (const float*)d_in[7];
  float* out_final  = (float*)d_out;                      // [T][H]
  float* out_logits = out_final + (size_t)T_TOK * HDIM;   // [T][E]

  char* ws = (char*)d_ws;
  int*   selk     = (int*)(ws + 0);          // 2048 i32
  float* cwk      = (float*)(ws + 8192);     // 2048 f32
  int*   rowidx   = (int*)(ws + 16384);      // 2048 i32
  int*   tokrow   = (int*)(ws + 24576);      // 4096 i32
  float* rowwgt   = (float*)(ws + 40960);    // 4096 f32
  int*   tile_tab = (int*)(ws + 57344);      // 32*2 i32
  unsigned short* xg  = (unsigned short*)(ws + 65536);                        // 4096x2048 bf16
  unsigned short* hg  = (unsigned short*)(ws + 65536 + 16777216);             // 3072x1408 bf16
  unsigned short* hsh = (unsigned short*)(ws + 65536 + 16777216 + 8650752);   // 1024x2816 bf16
  float* ydn = (float*)(ws + 65536 + 16777216 + 8650752 + 5767168);           // 3072x2048 f32

  router_kernel<<<T_TOK, 256, 0, stream>>>(x, rw, out_logits, selk, cwk);
  plan_kernel<<<1, 512, 0, stream>>>(selk, cwk, rowidx, tokrow, rowwgt, tile_tab);
  gather_kernel<<<ROWS_ALL, 256, 0, stream>>>(x, tokrow, xg);
  gu_kernel<<<dim3(ISH / 128, NT_TOT), 512, 0, stream>>>(
      xg, w_gate, w_up, sw_g, sw_u, rowwgt, tile_tab, hg, hsh);
  dn_kernel<<<dim3(HDIM / 128, NT_TOT), 512, 0, stream>>>(
      hg, hsh, w_down, sw_d, tile_tab, ydn, out_final);
  combine_kernel<<<T_TOK, 256, 0, stream>>>(ydn, rowidx, out_final);
}